// Round 5
// baseline (403.315 us; speedup 1.0000x reference)
//
#include <hip/hip_runtime.h>
#include <hip/hip_bf16.h>
#include <math.h>

#define B_    8
#define OLEN  1024
#define ILEN  4096
#define HDIM  256
#define LDA   40   // fallback-path LDS row stride (shorts)
#define KSPLIT 4   // context K-split (grid.y)

typedef __attribute__((ext_vector_type(8))) short bf16x8;
typedef __attribute__((ext_vector_type(4))) float f32x4;

__device__ inline unsigned pk_bf16(float x, float y) {
  union { __hip_bfloat162 h; unsigned u; } c;
  c.h = __float22bfloat162_rn(make_float2(x, y));
  return c.u;
}
__device__ inline short f2bf(float x) {
  union { __hip_bfloat16 h; short s; } c;
  c.h = __float2bfloat16(x);
  return c.s;
}

struct HiLo { uint4 hi, lo; };
__device__ inline HiLo split8(const float* __restrict__ p) {
  float4 v0 = *(const float4*)p;
  float4 v1 = *(const float4*)(p + 4);
  float f[8] = {v0.x, v0.y, v0.z, v0.w, v1.x, v1.y, v1.z, v1.w};
  unsigned hu[8]; float lo[8];
#pragma unroll
  for (int i = 0; i < 8; ++i) {
    unsigned u = __float_as_uint(f[i]);
    hu[i] = u & 0xffff0000u;
    lo[i] = f[i] - __uint_as_float(hu[i]);
  }
  HiLo r;
  r.hi = make_uint4((hu[0] >> 16) | hu[1], (hu[2] >> 16) | hu[3],
                    (hu[4] >> 16) | hu[5], (hu[6] >> 16) | hu[7]);
  r.lo = make_uint4(pk_bf16(lo[0], lo[1]), pk_bf16(lo[2], lo[3]),
                    pk_bf16(lo[4], lo[5]), pk_bf16(lo[6], lo[7]));
  return r;
}

__device__ inline void gl_lds16(const void* g, void* l) {
  __builtin_amdgcn_global_load_lds(
      (const __attribute__((address_space(1))) unsigned*)g,
      (__attribute__((address_space(3))) unsigned*)(l), 16, 0, 0);
}

// ---------------------------------------------------------------------------
// P0: Q -> Qhi/Qlo bf16 (linear).
// ---------------------------------------------------------------------------
__global__ __launch_bounds__(256) void k_prep_q(const float* __restrict__ Q,
                                                short* __restrict__ Qhi,
                                                short* __restrict__ Qlo) {
  const size_t idx = ((size_t)blockIdx.x * 256 + threadIdx.x) * 8;
  HiLo r = split8(&Q[idx]);
  *(uint4*)&Qhi[idx] = r.hi;
  *(uint4*)&Qlo[idx] = r.lo;
}

// ---------------------------------------------------------------------------
// P1: E -> Ehi/Elo (linear) + ET bf16 RNE transposed [b][h][i]. E read once.
// Masked 32-row tiles: skip E read/Ehi/Elo writes; ET := 0.
// ---------------------------------------------------------------------------
__global__ __launch_bounds__(256) void k_prep_e(const float* __restrict__ E,
                                                short* __restrict__ Ehi,
                                                short* __restrict__ Elo,
                                                short* __restrict__ ET,
                                                const int* __restrict__ len) {
  const int it = blockIdx.x, ht = blockIdx.y, b = blockIdx.z;
  const int L = len[b];
  const int t = threadIdx.x;
  if (it * 32 >= L) {  // fully masked tile: ET := 0 (block-uniform)
    const int h = t >> 3, i0 = (t & 7) * 4;
    *(uint2*)&ET[((size_t)(b * HDIM + ht * 32 + h)) * ILEN + it * 32 + i0] =
        make_uint2(0u, 0u);
    return;
  }
  __shared__ short Lsh[32][36];
  {
    const int i = t >> 3, h0 = (t & 7) * 4;
    const size_t gidx = ((size_t)(b * ILEN + it * 32 + i)) * HDIM + ht * 32 + h0;
    float4 v = *(const float4*)&E[gidx];
    float f[4] = {v.x, v.y, v.z, v.w};
    unsigned hs[4]; float lo[4];
#pragma unroll
    for (int j = 0; j < 4; ++j) {
      unsigned u = __float_as_uint(f[j]);
      hs[j] = u & 0xffff0000u;
      lo[j] = f[j] - __uint_as_float(hs[j]);
    }
    *(uint2*)&Ehi[gidx] = make_uint2((hs[0] >> 16) | hs[1], (hs[2] >> 16) | hs[3]);
    *(uint2*)&Elo[gidx] = make_uint2(pk_bf16(lo[0], lo[1]), pk_bf16(lo[2], lo[3]));
    Lsh[h0 + 0][i] = f2bf(f[0]);
    Lsh[h0 + 1][i] = f2bf(f[1]);
    Lsh[h0 + 2][i] = f2bf(f[2]);
    Lsh[h0 + 3][i] = f2bf(f[3]);
  }
  __syncthreads();
  {
    const int h = t >> 3, i0 = (t & 7) * 4;
    *(uint2*)&ET[((size_t)(b * HDIM + ht * 32 + h)) * ILEN + it * 32 + i0] =
        *(const uint2*)&Lsh[h][i0];
  }
}

// ---------------------------------------------------------------------------
// K1: scores, split-bf16 3-term MFMA, 128x128 tile, KC=32.
// Early-exit for fully masked i-tiles; epilogue emits per-tile row stats
// (max, sum exp(v - max)) over VALID columns into `stat`. Raw S written.
// ---------------------------------------------------------------------------
__global__ __launch_bounds__(256) void k_scores_pre(
    const short* __restrict__ Qhi, const short* __restrict__ Qlo,
    const short* __restrict__ Ehi, const short* __restrict__ Elo,
    float* __restrict__ S, float2* __restrict__ stat,
    const int* __restrict__ len) {
  const int it = blockIdx.x, ot = blockIdx.y, b = blockIdx.z;
  const int L = len[b];
  if (it * 128 >= L) return;  // block-uniform: whole tile masked

  const size_t qoff = ((size_t)b * OLEN + ot * 128) * HDIM;
  const size_t eoff = ((size_t)b * ILEN + it * 128) * HDIM;

  __shared__ __align__(16) short Ah[128 * 32], Al[128 * 32];
  __shared__ __align__(16) short Bh[128 * 32], Bl[128 * 32];

  const int t = threadIdx.x;
  const int w = t >> 6, l = t & 63;
  const int la = l & 15, quad = l >> 4;
  const int mw = (w & 1) * 64, nw = (w >> 1) * 64;

  int sgoff[2], sloff[2];
#pragma unroll
  for (int j = 0; j < 2; ++j) {
    const int row = (w * 2 + j) * 16 + (l >> 2);
    const int c = (l & 3) ^ ((row >> 1) & 3);
    sgoff[j] = row * HDIM + c * 8;
    sloff[j] = ((w * 2 + j) * 64 + l) * 8;
  }

  f32x4 acc[4][4] = {};

  for (int kc = 0; kc < HDIM; kc += 32) {
#pragma unroll
    for (int j = 0; j < 2; ++j) {
      const size_t ga = qoff + sgoff[j] + kc;
      const size_t gb = eoff + sgoff[j] + kc;
      gl_lds16(&Qhi[ga], &Ah[sloff[j]]);
      gl_lds16(&Qlo[ga], &Al[sloff[j]]);
      gl_lds16(&Ehi[gb], &Bh[sloff[j]]);
      gl_lds16(&Elo[gb], &Bl[sloff[j]]);
    }
    __syncthreads();
    bf16x8 ah[4], al[4];
#pragma unroll
    for (int mi = 0; mi < 4; ++mi) {
      const int row = mw + mi * 16 + la;
      const int off = row * 32 + (quad ^ ((row >> 1) & 3)) * 8;
      ah[mi] = *(const bf16x8*)&Ah[off];
      al[mi] = *(const bf16x8*)&Al[off];
    }
#pragma unroll
    for (int ni = 0; ni < 4; ++ni) {
      const int row = nw + ni * 16 + la;
      const int off = row * 32 + (quad ^ ((row >> 1) & 3)) * 8;
      bf16x8 bh = *(const bf16x8*)&Bh[off];
      bf16x8 bl = *(const bf16x8*)&Bl[off];
#pragma unroll
      for (int mi = 0; mi < 4; ++mi) {
        acc[mi][ni] = __builtin_amdgcn_mfma_f32_16x16x32_bf16(ah[mi], bh, acc[mi][ni], 0, 0, 0);
        acc[mi][ni] = __builtin_amdgcn_mfma_f32_16x16x32_bf16(ah[mi], bl, acc[mi][ni], 0, 0, 0);
        acc[mi][ni] = __builtin_amdgcn_mfma_f32_16x16x32_bf16(al[mi], bh, acc[mi][ni], 0, 0, 0);
      }
    }
    __syncthreads();
  }

  // raw S store
  float* Sb = S + ((size_t)b * OLEN + ot * 128) * (size_t)ILEN + it * 128;
#pragma unroll
  for (int mi = 0; mi < 4; ++mi)
#pragma unroll
    for (int ni = 0; ni < 4; ++ni)
#pragma unroll
      for (int r = 0; r < 4; ++r)
        Sb[(size_t)(mw + mi * 16 + quad * 4 + r) * ILEN + nw + ni * 16 + la] =
            acc[mi][ni][r];

  // ---- per-tile row stats over valid columns (alias Ah for reductions) ----
  float* SM = (float*)Ah;        // [2][128] per-n-half row max
  float* SS = SM + 256;          // [2][128] per-n-half row expsum
  const int colbase = it * 128 + nw;

  float rmax[4][4];
#pragma unroll
  for (int mi = 0; mi < 4; ++mi)
#pragma unroll
    for (int r = 0; r < 4; ++r) {
      float mx = -INFINITY;
#pragma unroll
      for (int ni = 0; ni < 4; ++ni)
        if (colbase + ni * 16 + la < L) mx = fmaxf(mx, acc[mi][ni][r]);
      rmax[mi][r] = mx;
    }
#pragma unroll
  for (int o = 1; o < 16; o <<= 1)
#pragma unroll
    for (int mi = 0; mi < 4; ++mi)
#pragma unroll
      for (int r = 0; r < 4; ++r)
        rmax[mi][r] = fmaxf(rmax[mi][r], __shfl_xor(rmax[mi][r], o, 64));
  if (la == 0) {
#pragma unroll
    for (int mi = 0; mi < 4; ++mi)
#pragma unroll
      for (int r = 0; r < 4; ++r)
        SM[(w >> 1) * 128 + mw + mi * 16 + quad * 4 + r] = rmax[mi][r];
  }
  __syncthreads();

  float rsum[4][4];
#pragma unroll
  for (int mi = 0; mi < 4; ++mi)
#pragma unroll
    for (int r = 0; r < 4; ++r) {
      const int row = mw + mi * 16 + quad * 4 + r;
      const float M = fmaxf(SM[row], SM[128 + row]);  // full tile row max
      float s = 0.f;
#pragma unroll
      for (int ni = 0; ni < 4; ++ni)
        if (colbase + ni * 16 + la < L) s += __expf(acc[mi][ni][r] - M);
      rsum[mi][r] = s;
    }
#pragma unroll
  for (int o = 1; o < 16; o <<= 1)
#pragma unroll
    for (int mi = 0; mi < 4; ++mi)
#pragma unroll
      for (int r = 0; r < 4; ++r)
        rsum[mi][r] += __shfl_xor(rsum[mi][r], o, 64);
  if (la == 0) {
#pragma unroll
    for (int mi = 0; mi < 4; ++mi)
#pragma unroll
      for (int r = 0; r < 4; ++r)
        SS[(w >> 1) * 128 + mw + mi * 16 + quad * 4 + r] = rsum[mi][r];
  }
  __syncthreads();

  if (t < 128) {
    const float m = fmaxf(SM[t], SM[128 + t]);
    const float s = SS[t] + SS[128 + t];
    stat[(size_t)it * (B_ * OLEN) + (size_t)b * OLEN + ot * 128 + t] =
        make_float2(m, s);
  }
}

// ---------------------------------------------------------------------------
// K2a: merge per-tile stats into per-row (max, 1/sum). Fully unrolled loads.
// ---------------------------------------------------------------------------
__global__ __launch_bounds__(128) void k_combine(const float2* __restrict__ stat,
                                                 float2* __restrict__ rowstat,
                                                 const int* __restrict__ len) {
  const int row = blockIdx.x * 128 + threadIdx.x;  // b*OLEN + o
  const int b = row >> 10;
  const int nt = (len[b] + 127) >> 7;  // valid tiles (>=1 since L>=1)
  float2 v[32];
#pragma unroll
  for (int it = 0; it < 32; ++it)
    v[it] = stat[(size_t)it * (B_ * OLEN) + row];
  float m = -INFINITY;
#pragma unroll
  for (int it = 0; it < 32; ++it)
    if (it < nt) m = fmaxf(m, v[it].x);
  float s = 0.f;
#pragma unroll
  for (int it = 0; it < 32; ++it)
    if (it < nt) s += v[it].y * __expf(v[it].x - m);
  rowstat[row] = make_float2(m, 1.f / s);
}

// ---------------------------------------------------------------------------
// K3 fused, NO-LDS + OWNERSHIP version: softmax-apply + attn write + context.
// M=64/block: each of 4 waves OWNS a disjoint 16-row slice (reads raw S,
// applies exp/norm once, writes attn once) and computes the FULL N=256 for
// those rows (acc[16]). No wave reads anything another wave writes =>
// race-free with ZERO barriers and ZERO LDS (R4 failed because two waves
// shared P rows in-place). ET B-fragments read directly (L2-hot).
// ---------------------------------------------------------------------------
__global__ __launch_bounds__(256) void k_context_fused(
    float* __restrict__ P, const short* __restrict__ ET,
    float* __restrict__ Cpart, const float2* __restrict__ rowstat,
    const int* __restrict__ len) {
  const int ot = blockIdx.x, ks = blockIdx.y, b = blockIdx.z;
  const int NC = ILEN / KSPLIT;  // 1024 cols per block
  float* Pb = P + ((size_t)b * OLEN + ot * 64) * (size_t)ILEN + ks * NC;
  const short* Tb = ET + (size_t)b * HDIM * ILEN + ks * NC;
  const int L = len[b];

  const int t = threadIdx.x;
  const int w = t >> 6, l = t & 63;
  const int la = l & 15, quad = l >> 4;
  const int mw = w * 16;      // this wave's exclusive 16-row slice

  const int arow = mw + la;   // A-row (and attn row) this lane handles
  const float2 st = rowstat[(size_t)b * OLEN + ot * 64 + arow];
  const float rm = st.x, rinv = st.y;

  f32x4 acc[16] = {};

  const int rem = L - ks * NC;
  const int nv = rem <= 0 ? 0 : (rem >= NC ? NC / 64 : (rem + 63) >> 6);

  // masked tail: attn := 0 (each wave zeroes only its own rows)
  {
    const float4 z = make_float4(0.f, 0.f, 0.f, 0.f);
    for (int ic = nv * 64; ic < NC; ic += 64) {
#pragma unroll
      for (int ki = 0; ki < 2; ++ki) {
        float* dst = &Pb[(size_t)arow * ILEN + ic + (ki * 4 + quad) * 8];
        *(float4*)(dst + 0) = z;
        *(float4*)(dst + 4) = z;
      }
    }
  }

  for (int c = 0; c < nv; ++c) {
    const int ic = c * 64;
    // --- A: raw S -> exp/normalize in-register; owner writes attn ---
    bf16x8 af[2];
#pragma unroll
    for (int ki = 0; ki < 2; ++ki) {
      float* src = &Pb[(size_t)arow * ILEN + ic + (ki * 4 + quad) * 8];
      float4 g0 = *(const float4*)(src + 0);
      float4 g1 = *(const float4*)(src + 4);
      float v[8] = {g0.x, g0.y, g0.z, g0.w, g1.x, g1.y, g1.z, g1.w};
      const int i0 = ks * NC + ic + (ki * 4 + quad) * 8;
#pragma unroll
      for (int j = 0; j < 8; ++j)
        v[j] = (i0 + j < L) ? __expf(v[j] - rm) * rinv : 0.f;
      *(float4*)(src + 0) = make_float4(v[0], v[1], v[2], v[3]);
      *(float4*)(src + 4) = make_float4(v[4], v[5], v[6], v[7]);
      uint4 pk = make_uint4(pk_bf16(v[0], v[1]), pk_bf16(v[2], v[3]),
                            pk_bf16(v[4], v[5]), pk_bf16(v[6], v[7]));
      union { uint4 u; bf16x8 h; } cv;
      cv.u = pk;
      af[ki] = cv.h;
    }
    // --- B direct from ET (L2-hot) + MFMA over full N=256 ---
#pragma unroll
    for (int ki = 0; ki < 2; ++ki)
#pragma unroll
      for (int ni = 0; ni < 16; ++ni) {
        const int hrow = ni * 16 + la;
        bf16x8 bfr =
            *(const bf16x8*)&Tb[(size_t)hrow * ILEN + ic + (ki * 4 + quad) * 8];
        acc[ni] = __builtin_amdgcn_mfma_f32_16x16x32_bf16(af[ki], bfr, acc[ni], 0, 0, 0);
      }
  }

  float* Cb = Cpart + (size_t)ks * (B_ * OLEN * HDIM) +
              ((size_t)b * OLEN + ot * 64) * HDIM;
#pragma unroll
  for (int ni = 0; ni < 16; ++ni)
#pragma unroll
    for (int r = 0; r < 4; ++r)
      Cb[(size_t)(mw + quad * 4 + r) * HDIM + ni * 16 + la] = acc[ni][r];
}

// K4: ctx = sum of KSPLIT Cpart slices
__global__ __launch_bounds__(256) void k_reduce(const float* __restrict__ Cp,
                                                float* __restrict__ ctx) {
  const size_t idx = ((size_t)blockIdx.x * 256 + threadIdx.x) * 8;
  const size_t n = (size_t)B_ * OLEN * HDIM;
  float a[8];
  {
    float4 a0 = *(const float4*)&Cp[idx];
    float4 a1 = *(const float4*)&Cp[idx + 4];
    a[0] = a0.x; a[1] = a0.y; a[2] = a0.z; a[3] = a0.w;
    a[4] = a1.x; a[5] = a1.y; a[6] = a1.z; a[7] = a1.w;
  }
#pragma unroll
  for (int k = 1; k < KSPLIT; ++k) {
    float4 b0 = *(const float4*)&Cp[(size_t)k * n + idx];
    float4 b1 = *(const float4*)&Cp[(size_t)k * n + idx + 4];
    a[0] += b0.x; a[1] += b0.y; a[2] += b0.z; a[3] += b0.w;
    a[4] += b1.x; a[5] += b1.y; a[6] += b1.z; a[7] += b1.w;
  }
  *(float4*)&ctx[idx]     = make_float4(a[0], a[1], a[2], a[3]);
  *(float4*)&ctx[idx + 4] = make_float4(a[4], a[5], a[6], a[7]);
}

// ===========================================================================
// Fallback path (ws too small) — R3-proven kernels.
// ===========================================================================
__global__ __launch_bounds__(256) void k_softmax(float* __restrict__ A,
                                                 const int* __restrict__ len) {
  const int row = blockIdx.x;
  const int b   = row >> 10;
  const int L   = len[b];
  float* p = A + (size_t)row * ILEN;
  const int t = threadIdx.x;

  float v[16];
#pragma unroll
  for (int k = 0; k < 4; ++k) {
    float4 x = *(const float4*)&p[4 * t + 1024 * k];
    v[4 * k + 0] = x.x; v[4 * k + 1] = x.y;
    v[4 * k + 2] = x.z; v[4 * k + 3] = x.w;
  }
  float m = -INFINITY;
#pragma unroll
  for (int k = 0; k < 4; ++k)
#pragma unroll
    for (int j = 0; j < 4; ++j) {
      const int i = 4 * t + 1024 * k + j;
      if (i < L) m = fmaxf(m, v[4 * k + j]);
    }
  for (int o = 32; o > 0; o >>= 1) m = fmaxf(m, __shfl_xor(m, o, 64));
  __shared__ float sm[4], ss[4];
  const int w = t >> 6;
  if ((t & 63) == 0) sm[w] = m;
  __syncthreads();
  m = fmaxf(fmaxf(sm[0], sm[1]), fmaxf(sm[2], sm[3]));
  float s = 0.f;
#pragma unroll
  for (int k = 0; k < 4; ++k)
#pragma unroll
    for (int j = 0; j < 4; ++j) {
      const int i = 4 * t + 1024 * k + j;
      float pv = (i < L) ? __expf(v[4 * k + j] - m) : 0.f;
      v[4 * k + j] = pv;
      s += pv;
    }
  for (int o = 32; o > 0; o >>= 1) s += __shfl_xor(s, o, 64);
  if ((t & 63) == 0) ss[w] = s;
  __syncthreads();
  s = ss[0] + ss[1] + ss[2] + ss[3];
  const float inv = 1.f / s;
#pragma unroll
  for (int k = 0; k < 4; ++k) {
    float4 x = make_float4(v[4 * k + 0] * inv, v[4 * k + 1] * inv,
                           v[4 * k + 2] * inv, v[4 * k + 3] * inv);
    *(float4*)&p[4 * t + 1024 * k] = x;
  }
}

__global__ __launch_bounds__(256) void k_etrans(const float* __restrict__ E,
                                                short* __restrict__ ET) {
  const int it = blockIdx.x, ht = blockIdx.y, b = blockIdx.z;
  __shared__ short Lsh[32][36];
  const int t = threadIdx.x;
  {
    const int i = t >> 3, h0 = (t & 7) * 4;
    float4 v = *(const float4*)&E[((size_t)(b * ILEN + it * 32 + i)) * HDIM + ht * 32 + h0];
    Lsh[h0 + 0][i] = f2bf(v.x);
    Lsh[h0 + 1][i] = f2bf(v.y);
    Lsh[h0 + 2][i] = f2bf(v.z);
    Lsh[h0 + 3][i] = f2bf(v.w);
  }
  __syncthreads();
  {
    const int h = t >> 3, i0 = (t & 7) * 4;
    *(uint2*)&ET[((size_t)(b * HDIM + ht * 32 + h)) * ILEN + it * 32 + i0] =
        *(const uint2*)&Lsh[h][i0];
  }
}

__global__ __launch_bounds__(256) void k_scores_split(const float* __restrict__ Q,
                                                      const float* __restrict__ E,
                                                      float* __restrict__ S) {
  const int b = blockIdx.z, ot = blockIdx.y, it = blockIdx.x;
  const float* Qb = Q + ((size_t)b * OLEN + ot * 64) * HDIM;
  const float* Eb = E + ((size_t)b * ILEN + it * 64) * HDIM;

  __shared__ __align__(16) short Ah[64 * LDA], Al[64 * LDA];
  __shared__ __align__(16) short Bh[64 * LDA], Bl[64 * LDA];

  const int t = threadIdx.x;
  const int w = t >> 6, l = t & 63;
  const int la = l & 15, quad = l >> 4;
  const int sr = t >> 2, sc = (t & 3) * 8;

  f32x4 acc[4] = {};

#pragma unroll
  for (int kc = 0; kc < HDIM; kc += 32) {
    HiLo qa = split8(&Qb[(size_t)sr * HDIM + kc + sc]);
    HiLo eb = split8(&Eb[(size_t)sr * HDIM + kc + sc]);
    *(uint4*)&Ah[sr * LDA + sc] = qa.hi;
    *(uint4*)&Al[sr * LDA + sc] = qa.lo;
    *(uint4*)&Bh[sr * LDA + sc] = eb.hi;
    *(uint4*)&Bl[sr * LDA + sc] = eb.lo;
    __syncthreads();
    bf16x8 ah = *(const bf16x8*)&Ah[(w * 16 + la) * LDA + quad * 8];
    bf16x8 al = *(const bf16x8*)&Al[(w * 16 + la) * LDA + quad * 8];
#pragma unroll
    for (int n = 0; n < 4; ++n) {
      bf16x8 bh = *(const bf16x8*)&Bh[(n * 16 + la) * LDA + quad * 8];
      bf16x8 bl = *(const bf16x8*)&Bl[(n * 16 + la) * LDA + quad * 8];
      acc[n] = __builtin_amdgcn_mfma_f32_16x16x32_bf16(ah, bh, acc[n], 0, 0, 0);
      acc[n] = __builtin_amdgcn_mfma_f32_16x16x32_bf16(ah, bl, acc[n], 0, 0, 0);
      acc[n] = __builtin_amdgcn_mfma_f32_16x16x32_bf16(al, bh, acc[n], 0, 0, 0);
    }
    __syncthreads();
  }

  float* Sb = S + ((size_t)b * OLEN + ot * 64) * (size_t)ILEN + it * 64;
#pragma unroll
  for (int n = 0; n < 4; ++n)
#pragma unroll
    for (int r = 0; r < 4; ++r)
      Sb[(size_t)(w * 16 + quad * 4 + r) * ILEN + n * 16 + la] = acc[n][r];
}

__global__ __launch_bounds__(256) void k_context_f32(const float* __restrict__ P,
                                                     const short* __restrict__ ET,
                                                     float* __restrict__ C) {
  const int ot = blockIdx.x, ht = blockIdx.y, b = blockIdx.z;
  const float* Pb = P + ((size_t)b * OLEN + ot * 64) * (size_t)ILEN;
  const short* Tb = ET + ((size_t)b * HDIM + ht * 64) * (size_t)ILEN;

  __shared__ __align__(16) short As[64 * LDA], Bs[64 * LDA];

  const int t = threadIdx.x;
  const int w = t >> 6, l = t & 63;
  const int la = l & 15, quad = l >> 4;
  const int sr = t >> 2, sc = (t & 3) * 8;

  f32x4 acc[4] = {};

  for (int ic = 0; ic < ILEN; ic += 32) {
    {
      float4 p0 = *(const float4*)&Pb[(size_t)sr * ILEN + ic + sc];
      float4 p1 = *(const float4*)&Pb[(size_t)sr * ILEN + ic + sc + 4];
      uint4 aw = make_uint4(pk_bf16(p0.x, p0.y), pk_bf16(p0.z, p0.w),
                            pk_bf16(p1.x, p1.y), pk_bf16(p1.z, p1.w));
      *(uint4*)&As[sr * LDA + sc] = aw;
      uint4 bw = *(const uint4*)&Tb[(size_t)sr * ILEN + ic + sc];
      *(uint4*)&Bs[sr * LDA + sc] = bw;
    }
    __syncthreads();
    bf16x8 a = *(const bf16x8*)&As[(w * 16 + la) * LDA + quad * 8];
#pragma unroll
    for (int n = 0; n < 4; ++n) {
      bf16x8 bb = *(const bf16x8*)&Bs[(n * 16 + la) * LDA + quad * 8];
      acc[n] = __builtin_amdgcn_mfma_f32_16x16x32_bf16(a, bb, acc[n], 0, 0, 0);
    }
    __syncthreads();
  }

  float* Cb = C + ((size_t)b * OLEN + ot * 64) * HDIM + ht * 64;
#pragma unroll
  for (int n = 0; n < 4; ++n)
#pragma unroll
    for (int r = 0; r < 4; ++r)
      Cb[(size_t)(w * 16 + quad * 4 + r) * HDIM + n * 16 + la] = acc[n][r];
}

extern "C" void kernel_launch(void* const* d_in, const int* in_sizes, int n_in,
                              void* d_out, int out_size, void* d_ws, size_t ws_size,
                              hipStream_t stream) {
  (void)in_sizes; (void)n_in; (void)out_size;
  const float* outp = (const float*)d_in[0];  // [B, OLEN, H]
  const float* enc  = (const float*)d_in[1];  // [B, ILEN, H]
  const int*   len  = (const int*)d_in[2];    // [B]

  float* ctx  = (float*)d_out;
  float* attn = ctx + (size_t)B_ * OLEN * HDIM;

  short* ws = (short*)d_ws;
  const size_t M = 1024 * 1024;
  // ws layout (shorts): ET[0,8M) Qhi[8M,10M) Qlo[10M,12M) Ehi[12M,20M) Elo[20M,28M)
  // = 56 MB total. Cpart (fp32, KSPLIT x 8.4 MB = 33.6 MB) overlays bytes
  // [16M, 49.6M) — dead Qhi/Qlo/Ehi + part of Elo, all dead after k_scores_pre.
  // Softmax stats live in the ctx OUTPUT buffer (dead until k_reduce):
  //   stat    = ctx[0 .. 2MB)      float2[32][B*OLEN]  (per-tile max/expsum)
  //   rowstat = ctx[2MB .. 2.06MB) float2[B*OLEN]      (per-row max, 1/sum)
  short* ET = ws;

  if (ws_size >= 56ull * 1024 * 1024) {
    short* Qhi = ws + 8 * M;
    short* Qlo = ws + 10 * M;
    short* Ehi = ws + 12 * M;
    short* Elo = ws + 20 * M;
    float* Cpart = (float*)(ws + 8 * M);  // byte offset 16 MB; 33.6 MB used
    float2* stat = (float2*)ctx;                                  // 2 MB
    float2* rowstat = stat + (size_t)(ILEN / 128) * B_ * OLEN;    // 64 KB

    k_prep_q<<<(B_ * OLEN * HDIM) / (256 * 8), 256, 0, stream>>>(outp, Qhi, Qlo);
    dim3 gp(ILEN / 32, HDIM / 32, B_);
    k_prep_e<<<gp, 256, 0, stream>>>(enc, Ehi, Elo, ET, len);
    dim3 g1(ILEN / 128, OLEN / 128, B_);
    k_scores_pre<<<g1, 256, 0, stream>>>(Qhi, Qlo, Ehi, Elo, attn, stat, len);
    k_combine<<<(B_ * OLEN) / 128, 128, 0, stream>>>(stat, rowstat, len);
    dim3 g3(OLEN / 64, KSPLIT, B_);
    k_context_fused<<<g3, 256, 0, stream>>>(attn, ET, Cpart, rowstat, len);
    k_reduce<<<(B_ * OLEN * HDIM) / (256 * 8), 256, 0, stream>>>(Cpart, ctx);
  } else {
    dim3 gt(ILEN / 32, HDIM / 32, B_);
    k_etrans<<<gt, 256, 0, stream>>>(enc, ET);
    k_scores_split<<<dim3(ILEN / 64, OLEN / 64, B_), 256, 0, stream>>>(outp, enc, attn);
    k_softmax<<<B_ * OLEN, 256, 0, stream>>>(attn, len);
    dim3 g3(OLEN / 64, HDIM / 64, B_);
    k_context_f32<<<g3, 256, 0, stream>>>(attn, ET, ctx);
  }
}

// Round 6
// 311.159 us; speedup vs baseline: 1.2962x; 1.2962x over previous
//
#include <hip/hip_runtime.h>
#include <hip/hip_bf16.h>
#include <math.h>

#define B_    8
#define OLEN  1024
#define ILEN  4096
#define HDIM  256
#define LDA   40   // fallback-path LDS row stride (shorts)
#define KSPLIT 4   // context K-split (grid.y)

typedef __attribute__((ext_vector_type(8))) short bf16x8;
typedef __attribute__((ext_vector_type(4))) float f32x4;

__device__ inline unsigned pk_bf16(float x, float y) {
  union { __hip_bfloat162 h; unsigned u; } c;
  c.h = __float22bfloat162_rn(make_float2(x, y));
  return c.u;
}
__device__ inline short f2bf(float x) {
  union { __hip_bfloat16 h; short s; } c;
  c.h = __float2bfloat16(x);
  return c.s;
}

struct HiLo { uint4 hi, lo; };
__device__ inline HiLo split8(const float* __restrict__ p) {
  float4 v0 = *(const float4*)p;
  float4 v1 = *(const float4*)(p + 4);
  float f[8] = {v0.x, v0.y, v0.z, v0.w, v1.x, v1.y, v1.z, v1.w};
  unsigned hu[8]; float lo[8];
#pragma unroll
  for (int i = 0; i < 8; ++i) {
    unsigned u = __float_as_uint(f[i]);
    hu[i] = u & 0xffff0000u;
    lo[i] = f[i] - __uint_as_float(hu[i]);
  }
  HiLo r;
  r.hi = make_uint4((hu[0] >> 16) | hu[1], (hu[2] >> 16) | hu[3],
                    (hu[4] >> 16) | hu[5], (hu[6] >> 16) | hu[7]);
  r.lo = make_uint4(pk_bf16(lo[0], lo[1]), pk_bf16(lo[2], lo[3]),
                    pk_bf16(lo[4], lo[5]), pk_bf16(lo[6], lo[7]));
  return r;
}

__device__ inline void gl_lds16(const void* g, void* l) {
  __builtin_amdgcn_global_load_lds(
      (const __attribute__((address_space(1))) unsigned*)g,
      (__attribute__((address_space(3))) unsigned*)(l), 16, 0, 0);
}

// ---------------------------------------------------------------------------
// P0: Q -> Qhi/Qlo bf16 (linear).
// ---------------------------------------------------------------------------
__global__ __launch_bounds__(256) void k_prep_q(const float* __restrict__ Q,
                                                short* __restrict__ Qhi,
                                                short* __restrict__ Qlo) {
  const size_t idx = ((size_t)blockIdx.x * 256 + threadIdx.x) * 8;
  HiLo r = split8(&Q[idx]);
  *(uint4*)&Qhi[idx] = r.hi;
  *(uint4*)&Qlo[idx] = r.lo;
}

// ---------------------------------------------------------------------------
// P1: E -> Ehi/Elo (linear) + ET bf16 RNE transposed [b][h][i]. E read once.
// Masked 32-row tiles: skip E read/Ehi/Elo writes; ET := 0.
// ---------------------------------------------------------------------------
__global__ __launch_bounds__(256) void k_prep_e(const float* __restrict__ E,
                                                short* __restrict__ Ehi,
                                                short* __restrict__ Elo,
                                                short* __restrict__ ET,
                                                const int* __restrict__ len) {
  const int it = blockIdx.x, ht = blockIdx.y, b = blockIdx.z;
  const int L = len[b];
  const int t = threadIdx.x;
  if (it * 32 >= L) {  // fully masked tile: ET := 0 (block-uniform)
    const int h = t >> 3, i0 = (t & 7) * 4;
    *(uint2*)&ET[((size_t)(b * HDIM + ht * 32 + h)) * ILEN + it * 32 + i0] =
        make_uint2(0u, 0u);
    return;
  }
  __shared__ short Lsh[32][36];
  {
    const int i = t >> 3, h0 = (t & 7) * 4;
    const size_t gidx = ((size_t)(b * ILEN + it * 32 + i)) * HDIM + ht * 32 + h0;
    float4 v = *(const float4*)&E[gidx];
    float f[4] = {v.x, v.y, v.z, v.w};
    unsigned hs[4]; float lo[4];
#pragma unroll
    for (int j = 0; j < 4; ++j) {
      unsigned u = __float_as_uint(f[j]);
      hs[j] = u & 0xffff0000u;
      lo[j] = f[j] - __uint_as_float(hs[j]);
    }
    *(uint2*)&Ehi[gidx] = make_uint2((hs[0] >> 16) | hs[1], (hs[2] >> 16) | hs[3]);
    *(uint2*)&Elo[gidx] = make_uint2(pk_bf16(lo[0], lo[1]), pk_bf16(lo[2], lo[3]));
    Lsh[h0 + 0][i] = f2bf(f[0]);
    Lsh[h0 + 1][i] = f2bf(f[1]);
    Lsh[h0 + 2][i] = f2bf(f[2]);
    Lsh[h0 + 3][i] = f2bf(f[3]);
  }
  __syncthreads();
  {
    const int h = t >> 3, i0 = (t & 7) * 4;
    *(uint2*)&ET[((size_t)(b * HDIM + ht * 32 + h)) * ILEN + it * 32 + i0] =
        *(const uint2*)&Lsh[h][i0];
  }
}

// ---------------------------------------------------------------------------
// K1: scores, split-bf16 3-term MFMA, 128x128 tile, KC=32.
// Early-exit for fully masked i-tiles; epilogue emits per-tile row stats
// (max, sum exp(v - max)) over VALID columns into `stat`. Raw S written.
// ---------------------------------------------------------------------------
__global__ __launch_bounds__(256) void k_scores_pre(
    const short* __restrict__ Qhi, const short* __restrict__ Qlo,
    const short* __restrict__ Ehi, const short* __restrict__ Elo,
    float* __restrict__ S, float2* __restrict__ stat,
    const int* __restrict__ len) {
  const int it = blockIdx.x, ot = blockIdx.y, b = blockIdx.z;
  const int L = len[b];
  if (it * 128 >= L) return;  // block-uniform: whole tile masked

  const size_t qoff = ((size_t)b * OLEN + ot * 128) * HDIM;
  const size_t eoff = ((size_t)b * ILEN + it * 128) * HDIM;

  __shared__ __align__(16) short Ah[128 * 32], Al[128 * 32];
  __shared__ __align__(16) short Bh[128 * 32], Bl[128 * 32];

  const int t = threadIdx.x;
  const int w = t >> 6, l = t & 63;
  const int la = l & 15, quad = l >> 4;
  const int mw = (w & 1) * 64, nw = (w >> 1) * 64;

  int sgoff[2], sloff[2];
#pragma unroll
  for (int j = 0; j < 2; ++j) {
    const int row = (w * 2 + j) * 16 + (l >> 2);
    const int c = (l & 3) ^ ((row >> 1) & 3);
    sgoff[j] = row * HDIM + c * 8;
    sloff[j] = ((w * 2 + j) * 64 + l) * 8;
  }

  f32x4 acc[4][4] = {};

  for (int kc = 0; kc < HDIM; kc += 32) {
#pragma unroll
    for (int j = 0; j < 2; ++j) {
      const size_t ga = qoff + sgoff[j] + kc;
      const size_t gb = eoff + sgoff[j] + kc;
      gl_lds16(&Qhi[ga], &Ah[sloff[j]]);
      gl_lds16(&Qlo[ga], &Al[sloff[j]]);
      gl_lds16(&Ehi[gb], &Bh[sloff[j]]);
      gl_lds16(&Elo[gb], &Bl[sloff[j]]);
    }
    __syncthreads();
    bf16x8 ah[4], al[4];
#pragma unroll
    for (int mi = 0; mi < 4; ++mi) {
      const int row = mw + mi * 16 + la;
      const int off = row * 32 + (quad ^ ((row >> 1) & 3)) * 8;
      ah[mi] = *(const bf16x8*)&Ah[off];
      al[mi] = *(const bf16x8*)&Al[off];
    }
#pragma unroll
    for (int ni = 0; ni < 4; ++ni) {
      const int row = nw + ni * 16 + la;
      const int off = row * 32 + (quad ^ ((row >> 1) & 3)) * 8;
      bf16x8 bh = *(const bf16x8*)&Bh[off];
      bf16x8 bl = *(const bf16x8*)&Bl[off];
#pragma unroll
      for (int mi = 0; mi < 4; ++mi) {
        acc[mi][ni] = __builtin_amdgcn_mfma_f32_16x16x32_bf16(ah[mi], bh, acc[mi][ni], 0, 0, 0);
        acc[mi][ni] = __builtin_amdgcn_mfma_f32_16x16x32_bf16(ah[mi], bl, acc[mi][ni], 0, 0, 0);
        acc[mi][ni] = __builtin_amdgcn_mfma_f32_16x16x32_bf16(al[mi], bh, acc[mi][ni], 0, 0, 0);
      }
    }
    __syncthreads();
  }

  // raw S store
  float* Sb = S + ((size_t)b * OLEN + ot * 128) * (size_t)ILEN + it * 128;
#pragma unroll
  for (int mi = 0; mi < 4; ++mi)
#pragma unroll
    for (int ni = 0; ni < 4; ++ni)
#pragma unroll
      for (int r = 0; r < 4; ++r)
        Sb[(size_t)(mw + mi * 16 + quad * 4 + r) * ILEN + nw + ni * 16 + la] =
            acc[mi][ni][r];

  // ---- per-tile row stats over valid columns (alias Ah for reductions) ----
  float* SM = (float*)Ah;        // [2][128] per-n-half row max
  float* SS = SM + 256;          // [2][128] per-n-half row expsum
  const int colbase = it * 128 + nw;

  float rmax[4][4];
#pragma unroll
  for (int mi = 0; mi < 4; ++mi)
#pragma unroll
    for (int r = 0; r < 4; ++r) {
      float mx = -INFINITY;
#pragma unroll
      for (int ni = 0; ni < 4; ++ni)
        if (colbase + ni * 16 + la < L) mx = fmaxf(mx, acc[mi][ni][r]);
      rmax[mi][r] = mx;
    }
#pragma unroll
  for (int o = 1; o < 16; o <<= 1)
#pragma unroll
    for (int mi = 0; mi < 4; ++mi)
#pragma unroll
      for (int r = 0; r < 4; ++r)
        rmax[mi][r] = fmaxf(rmax[mi][r], __shfl_xor(rmax[mi][r], o, 64));
  if (la == 0) {
#pragma unroll
    for (int mi = 0; mi < 4; ++mi)
#pragma unroll
      for (int r = 0; r < 4; ++r)
        SM[(w >> 1) * 128 + mw + mi * 16 + quad * 4 + r] = rmax[mi][r];
  }
  __syncthreads();

  float rsum[4][4];
#pragma unroll
  for (int mi = 0; mi < 4; ++mi)
#pragma unroll
    for (int r = 0; r < 4; ++r) {
      const int row = mw + mi * 16 + quad * 4 + r;
      const float M = fmaxf(SM[row], SM[128 + row]);  // full tile row max
      float s = 0.f;
#pragma unroll
      for (int ni = 0; ni < 4; ++ni)
        if (colbase + ni * 16 + la < L) s += __expf(acc[mi][ni][r] - M);
      rsum[mi][r] = s;
    }
#pragma unroll
  for (int o = 1; o < 16; o <<= 1)
#pragma unroll
    for (int mi = 0; mi < 4; ++mi)
#pragma unroll
      for (int r = 0; r < 4; ++r)
        rsum[mi][r] += __shfl_xor(rsum[mi][r], o, 64);
  if (la == 0) {
#pragma unroll
    for (int mi = 0; mi < 4; ++mi)
#pragma unroll
      for (int r = 0; r < 4; ++r)
        SS[(w >> 1) * 128 + mw + mi * 16 + quad * 4 + r] = rsum[mi][r];
  }
  __syncthreads();

  if (t < 128) {
    const float m = fmaxf(SM[t], SM[128 + t]);
    const float s = SS[t] + SS[128 + t];
    stat[(size_t)it * (B_ * OLEN) + (size_t)b * OLEN + ot * 128 + t] =
        make_float2(m, s);
  }
}

// ---------------------------------------------------------------------------
// K2a: merge per-tile stats into per-row (max, 1/sum). Fully unrolled loads.
// ---------------------------------------------------------------------------
__global__ __launch_bounds__(128) void k_combine(const float2* __restrict__ stat,
                                                 float2* __restrict__ rowstat,
                                                 const int* __restrict__ len) {
  const int row = blockIdx.x * 128 + threadIdx.x;  // b*OLEN + o
  const int b = row >> 10;
  const int nt = (len[b] + 127) >> 7;  // valid tiles (>=1 since L>=1)
  float2 v[32];
#pragma unroll
  for (int it = 0; it < 32; ++it)
    v[it] = stat[(size_t)it * (B_ * OLEN) + row];
  float m = -INFINITY;
#pragma unroll
  for (int it = 0; it < 32; ++it)
    if (it < nt) m = fmaxf(m, v[it].x);
  float s = 0.f;
#pragma unroll
  for (int it = 0; it < 32; ++it)
    if (it < nt) s += v[it].y * __expf(v[it].x - m);
  rowstat[row] = make_float2(m, 1.f / s);
}

// ---------------------------------------------------------------------------
// K3 fused: softmax-apply + attn write + context partial. M=32, N=256(full H),
// K-split=KSPLIT (1024 cols/block), KC=64. R3 structure (LDS-staged, coalesced
// gl_lds for ET -- R5's direct gathers were 64 cache lines/instr, -2.8x) with
// the T3 "minimum 2-phase" upgrade: double-buffered LDS, ONE barrier per
// chunk; STAGE(next) issues before MFMA(cur) so the whole staging latency
// (gl_lds B + raw-S load/exp) hides under compute. Barrier drains vmcnt ->
// next buffer ready; also orders all reads of cur before its overwrite.
// ---------------------------------------------------------------------------
__global__ __launch_bounds__(256) void k_context_fused(
    float* __restrict__ P, const short* __restrict__ ET,
    float* __restrict__ Cpart, const float2* __restrict__ rowstat,
    const int* __restrict__ len) {
  const int ot = blockIdx.x, ks = blockIdx.y, b = blockIdx.z;
  const int NC = ILEN / KSPLIT;  // 1024 cols per block
  float* Pb = P + ((size_t)b * OLEN + ot * 32) * (size_t)ILEN + ks * NC;
  const short* Tb = ET + (size_t)b * HDIM * ILEN + ks * NC;
  const int L = len[b];

  __shared__ __align__(16) short As[2][32 * 64];    // 2 x 4 KB
  __shared__ __align__(16) short Bs[2][256 * 64];   // 2 x 32 KB

  const int t = threadIdx.x;
  const int w = t >> 6, l = t & 63;
  const int la = l & 15, quad = l >> 4;
  const int mw = (w & 1) * 16, nw = (w >> 1) * 128;

  const int tr = t >> 3, tc = t & 7;   // staging: row 0..31, chunk 0..7 (8 floats)
  const float2 st = rowstat[(size_t)b * OLEN + ot * 32 + tr];
  const float rm = st.x, rinv = st.y;

  int bslot[8];
#pragma unroll
  for (int j = 0; j < 8; ++j) bslot[j] = w * 512 + j * 64 + l;

  f32x4 acc[8] = {};

  const int rem = L - ks * NC;
  const int nv = rem <= 0 ? 0 : (rem >= NC ? NC / 64 : (rem + 63) >> 6);

  // masked tail: attn := 0 (monotone mask => masked chunks are a suffix)
  for (int ic = nv * 64; ic < NC; ic += 64) {
    float* arow = &Pb[(size_t)tr * ILEN + ic + tc * 8];
    const float4 z = make_float4(0.f, 0.f, 0.f, 0.f);
    *(float4*)(arow + 0) = z;
    *(float4*)(arow + 4) = z;
  }

  // STAGE chunk c into buffer buf: gl_lds the ET tile (coalesced) + raw-S
  // load -> exp/norm -> attn write -> bf16 ds_write.
  auto STAGE = [&](int c, int buf) {
    const int ic = c * 64;
#pragma unroll
    for (int j = 0; j < 8; ++j) {
      const int s = bslot[j];
      const int row = s >> 3, pc = s & 7;
      const int cc = pc ^ (row & 7);
      gl_lds16(&Tb[(size_t)row * ILEN + ic + cc * 8], &Bs[buf][s * 8]);
    }
    {
      float* arow = &Pb[(size_t)tr * ILEN + ic + tc * 8];
      float4 g0 = *(const float4*)(arow + 0);
      float4 g1 = *(const float4*)(arow + 4);
      float v[8] = {g0.x, g0.y, g0.z, g0.w, g1.x, g1.y, g1.z, g1.w};
      const int i0 = ks * NC + ic + tc * 8;
#pragma unroll
      for (int j = 0; j < 8; ++j)
        v[j] = (i0 + j < L) ? __expf(v[j] - rm) * rinv : 0.f;
      *(float4*)(arow + 0) = make_float4(v[0], v[1], v[2], v[3]);
      *(float4*)(arow + 4) = make_float4(v[4], v[5], v[6], v[7]);
      uint4 w0 = make_uint4(pk_bf16(v[0], v[1]), pk_bf16(v[2], v[3]),
                            pk_bf16(v[4], v[5]), pk_bf16(v[6], v[7]));
      *(uint4*)&As[buf][tr * 64 + (tc ^ (tr & 7)) * 8] = w0;
    }
  };

  if (nv > 0) STAGE(0, 0);
  __syncthreads();

  for (int c = 0; c < nv; ++c) {
    const int cur = c & 1;
    if (c + 1 < nv) STAGE(c + 1, cur ^ 1);
    // --- MFMA on buffer cur ---
#pragma unroll
    for (int ki = 0; ki < 2; ++ki) {
      const int arow = mw + la;
      bf16x8 af = *(const bf16x8*)&As[cur][arow * 64 + ((ki * 4 + quad) ^ (arow & 7)) * 8];
#pragma unroll
      for (int ni = 0; ni < 8; ++ni) {
        const int row = nw + ni * 16 + la;
        bf16x8 bfr = *(const bf16x8*)&Bs[cur][row * 64 + ((ki * 4 + quad) ^ (row & 7)) * 8];
        acc[ni] = __builtin_amdgcn_mfma_f32_16x16x32_bf16(af, bfr, acc[ni], 0, 0, 0);
      }
    }
    __syncthreads();  // drains STAGE(next) + orders reads of cur before reuse
  }

  float* Cb = Cpart + (size_t)ks * (B_ * OLEN * HDIM) +
              ((size_t)b * OLEN + ot * 32) * HDIM;
#pragma unroll
  for (int ni = 0; ni < 8; ++ni)
#pragma unroll
    for (int r = 0; r < 4; ++r)
      Cb[(size_t)(mw + quad * 4 + r) * HDIM + nw + ni * 16 + la] = acc[ni][r];
}

// K4: ctx = sum of KSPLIT Cpart slices
__global__ __launch_bounds__(256) void k_reduce(const float* __restrict__ Cp,
                                                float* __restrict__ ctx) {
  const size_t idx = ((size_t)blockIdx.x * 256 + threadIdx.x) * 8;
  const size_t n = (size_t)B_ * OLEN * HDIM;
  float a[8];
  {
    float4 a0 = *(const float4*)&Cp[idx];
    float4 a1 = *(const float4*)&Cp[idx + 4];
    a[0] = a0.x; a[1] = a0.y; a[2] = a0.z; a[3] = a0.w;
    a[4] = a1.x; a[5] = a1.y; a[6] = a1.z; a[7] = a1.w;
  }
#pragma unroll
  for (int k = 1; k < KSPLIT; ++k) {
    float4 b0 = *(const float4*)&Cp[(size_t)k * n + idx];
    float4 b1 = *(const float4*)&Cp[(size_t)k * n + idx + 4];
    a[0] += b0.x; a[1] += b0.y; a[2] += b0.z; a[3] += b0.w;
    a[4] += b1.x; a[5] += b1.y; a[6] += b1.z; a[7] += b1.w;
  }
  *(float4*)&ctx[idx]     = make_float4(a[0], a[1], a[2], a[3]);
  *(float4*)&ctx[idx + 4] = make_float4(a[4], a[5], a[6], a[7]);
}

// ===========================================================================
// Fallback path (ws too small) — R3-proven kernels.
// ===========================================================================
__global__ __launch_bounds__(256) void k_softmax(float* __restrict__ A,
                                                 const int* __restrict__ len) {
  const int row = blockIdx.x;
  const int b   = row >> 10;
  const int L   = len[b];
  float* p = A + (size_t)row * ILEN;
  const int t = threadIdx.x;

  float v[16];
#pragma unroll
  for (int k = 0; k < 4; ++k) {
    float4 x = *(const float4*)&p[4 * t + 1024 * k];
    v[4 * k + 0] = x.x; v[4 * k + 1] = x.y;
    v[4 * k + 2] = x.z; v[4 * k + 3] = x.w;
  }
  float m = -INFINITY;
#pragma unroll
  for (int k = 0; k < 4; ++k)
#pragma unroll
    for (int j = 0; j < 4; ++j) {
      const int i = 4 * t + 1024 * k + j;
      if (i < L) m = fmaxf(m, v[4 * k + j]);
    }
  for (int o = 32; o > 0; o >>= 1) m = fmaxf(m, __shfl_xor(m, o, 64));
  __shared__ float sm[4], ss[4];
  const int w = t >> 6;
  if ((t & 63) == 0) sm[w] = m;
  __syncthreads();
  m = fmaxf(fmaxf(sm[0], sm[1]), fmaxf(sm[2], sm[3]));
  float s = 0.f;
#pragma unroll
  for (int k = 0; k < 4; ++k)
#pragma unroll
    for (int j = 0; j < 4; ++j) {
      const int i = 4 * t + 1024 * k + j;
      float pv = (i < L) ? __expf(v[4 * k + j] - m) : 0.f;
      v[4 * k + j] = pv;
      s += pv;
    }
  for (int o = 32; o > 0; o >>= 1) s += __shfl_xor(s, o, 64);
  if ((t & 63) == 0) ss[w] = s;
  __syncthreads();
  s = ss[0] + ss[1] + ss[2] + ss[3];
  const float inv = 1.f / s;
#pragma unroll
  for (int k = 0; k < 4; ++k) {
    float4 x = make_float4(v[4 * k + 0] * inv, v[4 * k + 1] * inv,
                           v[4 * k + 2] * inv, v[4 * k + 3] * inv);
    *(float4*)&p[4 * t + 1024 * k] = x;
  }
}

__global__ __launch_bounds__(256) void k_etrans(const float* __restrict__ E,
                                                short* __restrict__ ET) {
  const int it = blockIdx.x, ht = blockIdx.y, b = blockIdx.z;
  __shared__ short Lsh[32][36];
  const int t = threadIdx.x;
  {
    const int i = t >> 3, h0 = (t & 7) * 4;
    float4 v = *(const float4*)&E[((size_t)(b * ILEN + it * 32 + i)) * HDIM + ht * 32 + h0];
    Lsh[h0 + 0][i] = f2bf(v.x);
    Lsh[h0 + 1][i] = f2bf(v.y);
    Lsh[h0 + 2][i] = f2bf(v.z);
    Lsh[h0 + 3][i] = f2bf(v.w);
  }
  __syncthreads();
  {
    const int h = t >> 3, i0 = (t & 7) * 4;
    *(uint2*)&ET[((size_t)(b * HDIM + ht * 32 + h)) * ILEN + it * 32 + i0] =
        *(const uint2*)&Lsh[h][i0];
  }
}

__global__ __launch_bounds__(256) void k_scores_split(const float* __restrict__ Q,
                                                      const float* __restrict__ E,
                                                      float* __restrict__ S) {
  const int b = blockIdx.z, ot = blockIdx.y, it = blockIdx.x;
  const float* Qb = Q + ((size_t)b * OLEN + ot * 64) * HDIM;
  const float* Eb = E + ((size_t)b * ILEN + it * 64) * HDIM;

  __shared__ __align__(16) short Ah[64 * LDA], Al[64 * LDA];
  __shared__ __align__(16) short Bh[64 * LDA], Bl[64 * LDA];

  const int t = threadIdx.x;
  const int w = t >> 6, l = t & 63;
  const int la = l & 15, quad = l >> 4;
  const int sr = t >> 2, sc = (t & 3) * 8;

  f32x4 acc[4] = {};

#pragma unroll
  for (int kc = 0; kc < HDIM; kc += 32) {
    HiLo qa = split8(&Qb[(size_t)sr * HDIM + kc + sc]);
    HiLo eb = split8(&Eb[(size_t)sr * HDIM + kc + sc]);
    *(uint4*)&Ah[sr * LDA + sc] = qa.hi;
    *(uint4*)&Al[sr * LDA + sc] = qa.lo;
    *(uint4*)&Bh[sr * LDA + sc] = eb.hi;
    *(uint4*)&Bl[sr * LDA + sc] = eb.lo;
    __syncthreads();
    bf16x8 ah = *(const bf16x8*)&Ah[(w * 16 + la) * LDA + quad * 8];
    bf16x8 al = *(const bf16x8*)&Al[(w * 16 + la) * LDA + quad * 8];
#pragma unroll
    for (int n = 0; n < 4; ++n) {
      bf16x8 bh = *(const bf16x8*)&Bh[(n * 16 + la) * LDA + quad * 8];
      bf16x8 bl = *(const bf16x8*)&Bl[(n * 16 + la) * LDA + quad * 8];
      acc[n] = __builtin_amdgcn_mfma_f32_16x16x32_bf16(ah, bh, acc[n], 0, 0, 0);
      acc[n] = __builtin_amdgcn_mfma_f32_16x16x32_bf16(ah, bl, acc[n], 0, 0, 0);
      acc[n] = __builtin_amdgcn_mfma_f32_16x16x32_bf16(al, bh, acc[n], 0, 0, 0);
    }
    __syncthreads();
  }

  float* Sb = S + ((size_t)b * OLEN + ot * 64) * (size_t)ILEN + it * 64;
#pragma unroll
  for (int n = 0; n < 4; ++n)
#pragma unroll
    for (int r = 0; r < 4; ++r)
      Sb[(size_t)(w * 16 + quad * 4 + r) * ILEN + n * 16 + la] = acc[n][r];
}

__global__ __launch_bounds__(256) void k_context_f32(const float* __restrict__ P,
                                                     const short* __restrict__ ET,
                                                     float* __restrict__ C) {
  const int ot = blockIdx.x, ht = blockIdx.y, b = blockIdx.z;
  const float* Pb = P + ((size_t)b * OLEN + ot * 64) * (size_t)ILEN;
  const short* Tb = ET + ((size_t)b * HDIM + ht * 64) * (size_t)ILEN;

  __shared__ __align__(16) short As[64 * LDA], Bs[64 * LDA];

  const int t = threadIdx.x;
  const int w = t >> 6, l = t & 63;
  const int la = l & 15, quad = l >> 4;
  const int sr = t >> 2, sc = (t & 3) * 8;

  f32x4 acc[4] = {};

  for (int ic = 0; ic < ILEN; ic += 32) {
    {
      float4 p0 = *(const float4*)&Pb[(size_t)sr * ILEN + ic + sc];
      float4 p1 = *(const float4*)&Pb[(size_t)sr * ILEN + ic + sc + 4];
      uint4 aw = make_uint4(pk_bf16(p0.x, p0.y), pk_bf16(p0.z, p0.w),
                            pk_bf16(p1.x, p1.y), pk_bf16(p1.z, p1.w));
      *(uint4*)&As[sr * LDA + sc] = aw;
      uint4 bw = *(const uint4*)&Tb[(size_t)sr * ILEN + ic + sc];
      *(uint4*)&Bs[sr * LDA + sc] = bw;
    }
    __syncthreads();
    bf16x8 a = *(const bf16x8*)&As[(w * 16 + la) * LDA + quad * 8];
#pragma unroll
    for (int n = 0; n < 4; ++n) {
      bf16x8 bb = *(const bf16x8*)&Bs[(n * 16 + la) * LDA + quad * 8];
      acc[n] = __builtin_amdgcn_mfma_f32_16x16x32_bf16(a, bb, acc[n], 0, 0, 0);
    }
    __syncthreads();
  }

  float* Cb = C + ((size_t)b * OLEN + ot * 64) * HDIM + ht * 64;
#pragma unroll
  for (int n = 0; n < 4; ++n)
#pragma unroll
    for (int r = 0; r < 4; ++r)
      Cb[(size_t)(w * 16 + quad * 4 + r) * HDIM + n * 16 + la] = acc[n][r];
}

extern "C" void kernel_launch(void* const* d_in, const int* in_sizes, int n_in,
                              void* d_out, int out_size, void* d_ws, size_t ws_size,
                              hipStream_t stream) {
  (void)in_sizes; (void)n_in; (void)out_size;
  const float* outp = (const float*)d_in[0];  // [B, OLEN, H]
  const float* enc  = (const float*)d_in[1];  // [B, ILEN, H]
  const int*   len  = (const int*)d_in[2];    // [B]

  float* ctx  = (float*)d_out;
  float* attn = ctx + (size_t)B_ * OLEN * HDIM;

  short* ws = (short*)d_ws;
  const size_t M = 1024 * 1024;
  // ws layout (shorts): ET[0,8M) Qhi[8M,10M) Qlo[10M,12M) Ehi[12M,20M) Elo[20M,28M)
  // = 56 MB total. Cpart (fp32, KSPLIT x 8.4 MB = 33.6 MB) overlays bytes
  // [16M, 49.6M) — dead Qhi/Qlo/Ehi + part of Elo, all dead after k_scores_pre.
  // Softmax stats live in the ctx OUTPUT buffer (dead until k_reduce):
  //   stat    = ctx[0 .. 2MB)      float2[32][B*OLEN]  (per-tile max/expsum)
  //   rowstat = ctx[2MB .. 2.06MB) float2[B*OLEN]      (per-row max, 1/sum)
  short* ET = ws;

  if (ws_size >= 56ull * 1024 * 1024) {
    short* Qhi = ws + 8 * M;
    short* Qlo = ws + 10 * M;
    short* Ehi = ws + 12 * M;
    short* Elo = ws + 20 * M;
    float* Cpart = (float*)(ws + 8 * M);  // byte offset 16 MB; 33.6 MB used
    float2* stat = (float2*)ctx;                                  // 2 MB
    float2* rowstat = stat + (size_t)(ILEN / 128) * B_ * OLEN;    // 64 KB

    k_prep_q<<<(B_ * OLEN * HDIM) / (256 * 8), 256, 0, stream>>>(outp, Qhi, Qlo);
    dim3 gp(ILEN / 32, HDIM / 32, B_);
    k_prep_e<<<gp, 256, 0, stream>>>(enc, Ehi, Elo, ET, len);
    dim3 g1(ILEN / 128, OLEN / 128, B_);
    k_scores_pre<<<g1, 256, 0, stream>>>(Qhi, Qlo, Ehi, Elo, attn, stat, len);
    k_combine<<<(B_ * OLEN) / 128, 128, 0, stream>>>(stat, rowstat, len);
    dim3 g3(OLEN / 32, KSPLIT, B_);
    k_context_fused<<<g3, 256, 0, stream>>>(attn, ET, Cpart, rowstat, len);
    k_reduce<<<(B_ * OLEN * HDIM) / (256 * 8), 256, 0, stream>>>(Cpart, ctx);
  } else {
    dim3 gt(ILEN / 32, HDIM / 32, B_);
    k_etrans<<<gt, 256, 0, stream>>>(enc, ET);
    k_scores_split<<<dim3(ILEN / 64, OLEN / 64, B_), 256, 0, stream>>>(outp, enc, attn);
    k_softmax<<<B_ * OLEN, 256, 0, stream>>>(attn, len);
    dim3 g3(OLEN / 64, HDIM / 64, B_);
    k_context_f32<<<g3, 256, 0, stream>>>(attn, ET, ctx);
  }
}

// Round 8
// 299.134 us; speedup vs baseline: 1.3483x; 1.0402x over previous
//
#include <hip/hip_runtime.h>
#include <hip/hip_bf16.h>
#include <math.h>

#define B_    8
#define OLEN  1024
#define ILEN  4096
#define HDIM  256
#define LDA   40   // fallback-path LDS row stride (shorts)
#define KSPLIT 4   // context K-split (grid.y)

typedef __attribute__((ext_vector_type(8))) short bf16x8;
typedef __attribute__((ext_vector_type(4))) float f32x4;

__device__ inline unsigned pk_bf16(float x, float y) {
  union { __hip_bfloat162 h; unsigned u; } c;
  c.h = __float22bfloat162_rn(make_float2(x, y));
  return c.u;
}
__device__ inline short f2bf(float x) {
  union { __hip_bfloat16 h; short s; } c;
  c.h = __float2bfloat16(x);
  return c.s;
}

struct HiLo { uint4 hi, lo; };
__device__ inline HiLo split8(const float* __restrict__ p) {
  float4 v0 = *(const float4*)p;
  float4 v1 = *(const float4*)(p + 4);
  float f[8] = {v0.x, v0.y, v0.z, v0.w, v1.x, v1.y, v1.z, v1.w};
  unsigned hu[8]; float lo[8];
#pragma unroll
  for (int i = 0; i < 8; ++i) {
    unsigned u = __float_as_uint(f[i]);
    hu[i] = u & 0xffff0000u;
    lo[i] = f[i] - __uint_as_float(hu[i]);
  }
  HiLo r;
  r.hi = make_uint4((hu[0] >> 16) | hu[1], (hu[2] >> 16) | hu[3],
                    (hu[4] >> 16) | hu[5], (hu[6] >> 16) | hu[7]);
  r.lo = make_uint4(pk_bf16(lo[0], lo[1]), pk_bf16(lo[2], lo[3]),
                    pk_bf16(lo[4], lo[5]), pk_bf16(lo[6], lo[7]));
  return r;
}

__device__ inline void gl_lds16(const void* g, void* l) {
  __builtin_amdgcn_global_load_lds(
      (const __attribute__((address_space(1))) unsigned*)g,
      (__attribute__((address_space(3))) unsigned*)(l), 16, 0, 0);
}

// ---------------------------------------------------------------------------
// P0+P1 merged: grid (128, 9, 8).
//   y<8 : E -> Ehi/Elo (linear) + ET bf16 transposed (masked tiles: ET:=0).
//   y==8: Q -> Qhi/Qlo bf16 (linear), ONE 2048-float chunk per block
//         (128 x-blocks * 8 z-blocks = 1024 chunks = 2.1M floats exactly;
//         R7's 4-chunk loop overran Q by 4x -> memory fault).
// ---------------------------------------------------------------------------
__global__ __launch_bounds__(256) void k_prep(const float* __restrict__ Q,
                                              const float* __restrict__ E,
                                              short* __restrict__ Qhi,
                                              short* __restrict__ Qlo,
                                              short* __restrict__ Ehi,
                                              short* __restrict__ Elo,
                                              short* __restrict__ ET,
                                              const int* __restrict__ len) {
  const int t = threadIdx.x;
  if (blockIdx.y == 8) {  // --- Q strip (block-uniform branch) ---
    const int flat = blockIdx.z * 128 + blockIdx.x;  // 0..1023
    const size_t idx = (size_t)flat * 2048 + t * 8;
    HiLo r = split8(&Q[idx]);
    *(uint4*)&Qhi[idx] = r.hi;
    *(uint4*)&Qlo[idx] = r.lo;
    return;
  }
  const int it = blockIdx.x, ht = blockIdx.y, b = blockIdx.z;
  const int L = len[b];
  if (it * 32 >= L) {  // fully masked tile: ET := 0 (block-uniform)
    const int h = t >> 3, i0 = (t & 7) * 4;
    *(uint2*)&ET[((size_t)(b * HDIM + ht * 32 + h)) * ILEN + it * 32 + i0] =
        make_uint2(0u, 0u);
    return;
  }
  __shared__ short Lsh[32][36];
  {
    const int i = t >> 3, h0 = (t & 7) * 4;
    const size_t gidx = ((size_t)(b * ILEN + it * 32 + i)) * HDIM + ht * 32 + h0;
    float4 v = *(const float4*)&E[gidx];
    float f[4] = {v.x, v.y, v.z, v.w};
    unsigned hs[4]; float lo[4];
#pragma unroll
    for (int j = 0; j < 4; ++j) {
      unsigned u = __float_as_uint(f[j]);
      hs[j] = u & 0xffff0000u;
      lo[j] = f[j] - __uint_as_float(hs[j]);
    }
    *(uint2*)&Ehi[gidx] = make_uint2((hs[0] >> 16) | hs[1], (hs[2] >> 16) | hs[3]);
    *(uint2*)&Elo[gidx] = make_uint2(pk_bf16(lo[0], lo[1]), pk_bf16(lo[2], lo[3]));
    Lsh[h0 + 0][i] = f2bf(f[0]);
    Lsh[h0 + 1][i] = f2bf(f[1]);
    Lsh[h0 + 2][i] = f2bf(f[2]);
    Lsh[h0 + 3][i] = f2bf(f[3]);
  }
  __syncthreads();
  {
    const int h = t >> 3, i0 = (t & 7) * 4;
    *(uint2*)&ET[((size_t)(b * HDIM + ht * 32 + h)) * ILEN + it * 32 + i0] =
        *(const uint2*)&Lsh[h][i0];
  }
}

// ---------------------------------------------------------------------------
// K1: scores, split-bf16 3-term MFMA, 128x128 tile, KC=32.
// Early-exit for fully masked i-tiles. Epilogue: tile row max -> store
// p = exp(S - m_tile) (fp32, reuses the exp the stats phase needs anyway)
// + per-tile row stats (max, expsum over VALID cols) into `stat`.
// ---------------------------------------------------------------------------
__global__ __launch_bounds__(256) void k_scores_pre(
    const short* __restrict__ Qhi, const short* __restrict__ Qlo,
    const short* __restrict__ Ehi, const short* __restrict__ Elo,
    float* __restrict__ S, float2* __restrict__ stat,
    const int* __restrict__ len) {
  const int it = blockIdx.x, ot = blockIdx.y, b = blockIdx.z;
  const int L = len[b];
  if (it * 128 >= L) return;  // block-uniform: whole tile masked

  const size_t qoff = ((size_t)b * OLEN + ot * 128) * HDIM;
  const size_t eoff = ((size_t)b * ILEN + it * 128) * HDIM;

  __shared__ __align__(16) short Ah[128 * 32], Al[128 * 32];
  __shared__ __align__(16) short Bh[128 * 32], Bl[128 * 32];

  const int t = threadIdx.x;
  const int w = t >> 6, l = t & 63;
  const int la = l & 15, quad = l >> 4;
  const int mw = (w & 1) * 64, nw = (w >> 1) * 64;

  int sgoff[2], sloff[2];
#pragma unroll
  for (int j = 0; j < 2; ++j) {
    const int row = (w * 2 + j) * 16 + (l >> 2);
    const int c = (l & 3) ^ ((row >> 1) & 3);
    sgoff[j] = row * HDIM + c * 8;
    sloff[j] = ((w * 2 + j) * 64 + l) * 8;
  }

  f32x4 acc[4][4] = {};

  for (int kc = 0; kc < HDIM; kc += 32) {
#pragma unroll
    for (int j = 0; j < 2; ++j) {
      const size_t ga = qoff + sgoff[j] + kc;
      const size_t gb = eoff + sgoff[j] + kc;
      gl_lds16(&Qhi[ga], &Ah[sloff[j]]);
      gl_lds16(&Qlo[ga], &Al[sloff[j]]);
      gl_lds16(&Ehi[gb], &Bh[sloff[j]]);
      gl_lds16(&Elo[gb], &Bl[sloff[j]]);
    }
    __syncthreads();
    bf16x8 ah[4], al[4];
#pragma unroll
    for (int mi = 0; mi < 4; ++mi) {
      const int row = mw + mi * 16 + la;
      const int off = row * 32 + (quad ^ ((row >> 1) & 3)) * 8;
      ah[mi] = *(const bf16x8*)&Ah[off];
      al[mi] = *(const bf16x8*)&Al[off];
    }
#pragma unroll
    for (int ni = 0; ni < 4; ++ni) {
      const int row = nw + ni * 16 + la;
      const int off = row * 32 + (quad ^ ((row >> 1) & 3)) * 8;
      bf16x8 bh = *(const bf16x8*)&Bh[off];
      bf16x8 bl = *(const bf16x8*)&Bl[off];
#pragma unroll
      for (int mi = 0; mi < 4; ++mi) {
        acc[mi][ni] = __builtin_amdgcn_mfma_f32_16x16x32_bf16(ah[mi], bh, acc[mi][ni], 0, 0, 0);
        acc[mi][ni] = __builtin_amdgcn_mfma_f32_16x16x32_bf16(ah[mi], bl, acc[mi][ni], 0, 0, 0);
        acc[mi][ni] = __builtin_amdgcn_mfma_f32_16x16x32_bf16(al[mi], bh, acc[mi][ni], 0, 0, 0);
      }
    }
    __syncthreads();
  }

  // ---- epilogue: max -> p-store -> expsum -> stats (alias Ah) ----
  float* SM = (float*)Ah;        // [2][128] per-n-half row max
  float* SS = SM + 256;          // [2][128] per-n-half row expsum
  const int colbase = it * 128 + nw;

  float rmax[4][4];
#pragma unroll
  for (int mi = 0; mi < 4; ++mi)
#pragma unroll
    for (int r = 0; r < 4; ++r) {
      float mx = -INFINITY;
#pragma unroll
      for (int ni = 0; ni < 4; ++ni)
        if (colbase + ni * 16 + la < L) mx = fmaxf(mx, acc[mi][ni][r]);
      rmax[mi][r] = mx;
    }
#pragma unroll
  for (int o = 1; o < 16; o <<= 1)
#pragma unroll
    for (int mi = 0; mi < 4; ++mi)
#pragma unroll
      for (int r = 0; r < 4; ++r)
        rmax[mi][r] = fmaxf(rmax[mi][r], __shfl_xor(rmax[mi][r], o, 64));
  if (la == 0) {
#pragma unroll
    for (int mi = 0; mi < 4; ++mi)
#pragma unroll
      for (int r = 0; r < 4; ++r)
        SM[(w >> 1) * 128 + mw + mi * 16 + quad * 4 + r] = rmax[mi][r];
  }
  __syncthreads();

  float* Sb = S + ((size_t)b * OLEN + ot * 128) * (size_t)ILEN + it * 128;
  float rsum[4][4];
#pragma unroll
  for (int mi = 0; mi < 4; ++mi)
#pragma unroll
    for (int r = 0; r < 4; ++r) {
      const int row = mw + mi * 16 + quad * 4 + r;
      const float M = fmaxf(SM[row], SM[128 + row]);  // full tile row max
      float s = 0.f;
#pragma unroll
      for (int ni = 0; ni < 4; ++ni) {
        const float p = __expf(acc[mi][ni][r] - M);
        Sb[(size_t)row * ILEN + nw + ni * 16 + la] = p;  // p-store (all cols)
        if (colbase + ni * 16 + la < L) s += p;
      }
      rsum[mi][r] = s;
    }
#pragma unroll
  for (int o = 1; o < 16; o <<= 1)
#pragma unroll
    for (int mi = 0; mi < 4; ++mi)
#pragma unroll
      for (int r = 0; r < 4; ++r)
        rsum[mi][r] += __shfl_xor(rsum[mi][r], o, 64);
  if (la == 0) {
#pragma unroll
    for (int mi = 0; mi < 4; ++mi)
#pragma unroll
      for (int r = 0; r < 4; ++r)
        SS[(w >> 1) * 128 + mw + mi * 16 + quad * 4 + r] = rsum[mi][r];
  }
  __syncthreads();

  if (t < 128) {
    const float m = fmaxf(SM[t], SM[128 + t]);
    const float s = SS[t] + SS[128 + t];
    stat[(size_t)it * (B_ * OLEN) + (size_t)b * OLEN + ot * 128 + t] =
        make_float2(m, s);
  }
}

// ---------------------------------------------------------------------------
// K3 fused: combine + softmax-apply + attn write + context partial.
// R3-proven single-buffer structure (M=32, N=256, KC=64, KSPLIT=4).
// Prologue (replaces k_combine): 32 rows x 8 lanes reduce the 32 tile stats
// to (m_row, inv_row) and precompute per-(row, local-tile) scale
// = exp(m_tile - m_row) * inv_row into a 1 KB LDS table. Staging is then
// load p -> mul scale -> select -> attn store + bf16 pack (no exp).
// ---------------------------------------------------------------------------
__global__ __launch_bounds__(256) void k_context_fused(
    float* __restrict__ P, const short* __restrict__ ET,
    float* __restrict__ Cpart, const float2* __restrict__ stat,
    const int* __restrict__ len) {
  const int ot = blockIdx.x, ks = blockIdx.y, b = blockIdx.z;
  const int NC = ILEN / KSPLIT;  // 1024 cols per block
  float* Pb = P + ((size_t)b * OLEN + ot * 32) * (size_t)ILEN + ks * NC;
  const short* Tb = ET + (size_t)b * HDIM * ILEN + ks * NC;
  const int L = len[b];

  __shared__ __align__(16) short As[32 * 64];    // 4 KB
  __shared__ __align__(16) short Bs[256 * 64];   // 32 KB
  __shared__ float ssc[32][8];                   // 1 KB scale table

  const int t = threadIdx.x;
  const int w = t >> 6, l = t & 63;
  const int la = l & 15, quad = l >> 4;
  const int mw = (w & 1) * 16, nw = (w >> 1) * 128;
  const int tr = t >> 3, tc = t & 7;   // row 0..31, chunk 0..7

  // ---- prologue: per-row softmax stats + scale table ----
  {
    const int rowg = b * OLEN + ot * 32 + tr;
    const int nt = (L + 127) >> 7;  // valid 128-tiles (>=1)
    float2 v0 = stat[(size_t)(tc + 0)  * (B_ * OLEN) + rowg];
    float2 v1 = stat[(size_t)(tc + 8)  * (B_ * OLEN) + rowg];
    float2 v2 = stat[(size_t)(tc + 16) * (B_ * OLEN) + rowg];
    float2 v3 = stat[(size_t)(tc + 24) * (B_ * OLEN) + rowg];
    float m = -INFINITY;
    if (tc + 0  < nt) m = fmaxf(m, v0.x);
    if (tc + 8  < nt) m = fmaxf(m, v1.x);
    if (tc + 16 < nt) m = fmaxf(m, v2.x);
    if (tc + 24 < nt) m = fmaxf(m, v3.x);
#pragma unroll
    for (int o = 1; o < 8; o <<= 1) m = fmaxf(m, __shfl_xor(m, o, 64));
    float s = 0.f;
    if (tc + 0  < nt) s += v0.y * __expf(v0.x - m);
    if (tc + 8  < nt) s += v1.y * __expf(v1.x - m);
    if (tc + 16 < nt) s += v2.y * __expf(v2.x - m);
    if (tc + 24 < nt) s += v3.y * __expf(v3.x - m);
#pragma unroll
    for (int o = 1; o < 8; o <<= 1) s += __shfl_xor(s, o, 64);
    const float inv = 1.f / s;
    // local tile tc corresponds to global tile ks*8 + tc
    float2 vt = (ks == 0) ? v0 : (ks == 1) ? v1 : (ks == 2) ? v2 : v3;
    ssc[tr][tc] = __expf(vt.x - m) * inv;   // garbage for invalid tiles: never read
  }
  __syncthreads();

  int bslot[8];
#pragma unroll
  for (int j = 0; j < 8; ++j) bslot[j] = w * 512 + j * 64 + l;

  f32x4 acc[8] = {};

  const int rem = L - ks * NC;
  const int nv = rem <= 0 ? 0 : (rem >= NC ? NC / 64 : (rem + 63) >> 6);

  // masked tail: attn := 0 (monotone mask => masked chunks are a suffix)
  for (int ic = nv * 64; ic < NC; ic += 64) {
    float* arow = &Pb[(size_t)tr * ILEN + ic + tc * 8];
    const float4 z = make_float4(0.f, 0.f, 0.f, 0.f);
    *(float4*)(arow + 0) = z;
    *(float4*)(arow + 4) = z;
  }

  for (int c = 0; c < nv; ++c) {
    const int ic = c * 64;
    // --- stage B (pure copy, async) ---
#pragma unroll
    for (int j = 0; j < 8; ++j) {
      const int s = bslot[j];
      const int row = s >> 3, pc = s & 7;
      const int cc = pc ^ (row & 7);
      gl_lds16(&Tb[(size_t)row * ILEN + ic + cc * 8], &Bs[s * 8]);
    }
    // --- stage A: p load (overlaps gl_lds), scale, attn write, bf16 -> LDS ---
    {
      float* arow = &Pb[(size_t)tr * ILEN + ic + tc * 8];
      float4 g0 = *(const float4*)(arow + 0);
      float4 g1 = *(const float4*)(arow + 4);
      const float sc = ssc[tr][c >> 1];
      float v[8] = {g0.x, g0.y, g0.z, g0.w, g1.x, g1.y, g1.z, g1.w};
      const int i0 = ks * NC + ic + tc * 8;
#pragma unroll
      for (int j = 0; j < 8; ++j)
        v[j] = (i0 + j < L) ? v[j] * sc : 0.f;
      *(float4*)(arow + 0) = make_float4(v[0], v[1], v[2], v[3]);
      *(float4*)(arow + 4) = make_float4(v[4], v[5], v[6], v[7]);
      uint4 w0 = make_uint4(pk_bf16(v[0], v[1]), pk_bf16(v[2], v[3]),
                            pk_bf16(v[4], v[5]), pk_bf16(v[6], v[7]));
      *(uint4*)&As[tr * 64 + (tc ^ (tr & 7)) * 8] = w0;
    }
    __syncthreads();
    // --- MFMA ---
#pragma unroll
    for (int ki = 0; ki < 2; ++ki) {
      const int arow = mw + la;
      bf16x8 af = *(const bf16x8*)&As[arow * 64 + ((ki * 4 + quad) ^ (arow & 7)) * 8];
#pragma unroll
      for (int ni = 0; ni < 8; ++ni) {
        const int row = nw + ni * 16 + la;
        bf16x8 bfr = *(const bf16x8*)&Bs[row * 64 + ((ki * 4 + quad) ^ (row & 7)) * 8];
        acc[ni] = __builtin_amdgcn_mfma_f32_16x16x32_bf16(af, bfr, acc[ni], 0, 0, 0);
      }
    }
    __syncthreads();
  }

  float* Cb = Cpart + (size_t)ks * (B_ * OLEN * HDIM) +
              ((size_t)b * OLEN + ot * 32) * HDIM;
#pragma unroll
  for (int ni = 0; ni < 8; ++ni)
#pragma unroll
    for (int r = 0; r < 4; ++r)
      Cb[(size_t)(mw + quad * 4 + r) * HDIM + nw + ni * 16 + la] = acc[ni][r];
}

// K4: ctx = sum of KSPLIT Cpart slices
__global__ __launch_bounds__(256) void k_reduce(const float* __restrict__ Cp,
                                                float* __restrict__ ctx) {
  const size_t idx = ((size_t)blockIdx.x * 256 + threadIdx.x) * 8;
  const size_t n = (size_t)B_ * OLEN * HDIM;
  float a[8];
  {
    float4 a0 = *(const float4*)&Cp[idx];
    float4 a1 = *(const float4*)&Cp[idx + 4];
    a[0] = a0.x; a[1] = a0.y; a[2] = a0.z; a[3] = a0.w;
    a[4] = a1.x; a[5] = a1.y; a[6] = a1.z; a[7] = a1.w;
  }
#pragma unroll
  for (int k = 1; k < KSPLIT; ++k) {
    float4 b0 = *(const float4*)&Cp[(size_t)k * n + idx];
    float4 b1 = *(const float4*)&Cp[(size_t)k * n + idx + 4];
    a[0] += b0.x; a[1] += b0.y; a[2] += b0.z; a[3] += b0.w;
    a[4] += b1.x; a[5] += b1.y; a[6] += b1.z; a[7] += b1.w;
  }
  *(float4*)&ctx[idx]     = make_float4(a[0], a[1], a[2], a[3]);
  *(float4*)&ctx[idx + 4] = make_float4(a[4], a[5], a[6], a[7]);
}

// ===========================================================================
// Fallback path (ws too small) — R3-proven kernels.
// ===========================================================================
__global__ __launch_bounds__(256) void k_softmax(float* __restrict__ A,
                                                 const int* __restrict__ len) {
  const int row = blockIdx.x;
  const int b   = row >> 10;
  const int L   = len[b];
  float* p = A + (size_t)row * ILEN;
  const int t = threadIdx.x;

  float v[16];
#pragma unroll
  for (int k = 0; k < 4; ++k) {
    float4 x = *(const float4*)&p[4 * t + 1024 * k];
    v[4 * k + 0] = x.x; v[4 * k + 1] = x.y;
    v[4 * k + 2] = x.z; v[4 * k + 3] = x.w;
  }
  float m = -INFINITY;
#pragma unroll
  for (int k = 0; k < 4; ++k)
#pragma unroll
    for (int j = 0; j < 4; ++j) {
      const int i = 4 * t + 1024 * k + j;
      if (i < L) m = fmaxf(m, v[4 * k + j]);
    }
  for (int o = 32; o > 0; o >>= 1) m = fmaxf(m, __shfl_xor(m, o, 64));
  __shared__ float sm[4], ss[4];
  const int w = t >> 6;
  if ((t & 63) == 0) sm[w] = m;
  __syncthreads();
  m = fmaxf(fmaxf(sm[0], sm[1]), fmaxf(sm[2], sm[3]));
  float s = 0.f;
#pragma unroll
  for (int k = 0; k < 4; ++k)
#pragma unroll
    for (int j = 0; j < 4; ++j) {
      const int i = 4 * t + 1024 * k + j;
      float pv = (i < L) ? __expf(v[4 * k + j] - m) : 0.f;
      v[4 * k + j] = pv;
      s += pv;
    }
  for (int o = 32; o > 0; o >>= 1) s += __shfl_xor(s, o, 64);
  if ((t & 63) == 0) ss[w] = s;
  __syncthreads();
  s = ss[0] + ss[1] + ss[2] + ss[3];
  const float inv = 1.f / s;
#pragma unroll
  for (int k = 0; k < 4; ++k) {
    float4 x = make_float4(v[4 * k + 0] * inv, v[4 * k + 1] * inv,
                           v[4 * k + 2] * inv, v[4 * k + 3] * inv);
    *(float4*)&p[4 * t + 1024 * k] = x;
  }
}

__global__ __launch_bounds__(256) void k_etrans(const float* __restrict__ E,
                                                short* __restrict__ ET) {
  const int it = blockIdx.x, ht = blockIdx.y, b = blockIdx.z;
  __shared__ short Lsh[32][36];
  const int t = threadIdx.x;
  {
    const int i = t >> 3, h0 = (t & 7) * 4;
    float4 v = *(const float4*)&E[((size_t)(b * ILEN + it * 32 + i)) * HDIM + ht * 32 + h0];
    Lsh[h0 + 0][i] = f2bf(v.x);
    Lsh[h0 + 1][i] = f2bf(v.y);
    Lsh[h0 + 2][i] = f2bf(v.z);
    Lsh[h0 + 3][i] = f2bf(v.w);
  }
  __syncthreads();
  {
    const int h = t >> 3, i0 = (t & 7) * 4;
    *(uint2*)&ET[((size_t)(b * HDIM + ht * 32 + h)) * ILEN + it * 32 + i0] =
        *(const uint2*)&Lsh[h][i0];
  }
}

__global__ __launch_bounds__(256) void k_scores_split(const float* __restrict__ Q,
                                                      const float* __restrict__ E,
                                                      float* __restrict__ S) {
  const int b = blockIdx.z, ot = blockIdx.y, it = blockIdx.x;
  const float* Qb = Q + ((size_t)b * OLEN + ot * 64) * HDIM;
  const float* Eb = E + ((size_t)b * ILEN + it * 64) * HDIM;

  __shared__ __align__(16) short Ah[64 * LDA], Al[64 * LDA];
  __shared__ __align__(16) short Bh[64 * LDA], Bl[64 * LDA];

  const int t = threadIdx.x;
  const int w = t >> 6, l = t & 63;
  const int la = l & 15, quad = l >> 4;
  const int sr = t >> 2, sc = (t & 3) * 8;

  f32x4 acc[4] = {};

#pragma unroll
  for (int kc = 0; kc < HDIM; kc += 32) {
    HiLo qa = split8(&Qb[(size_t)sr * HDIM + kc + sc]);
    HiLo eb = split8(&Eb[(size_t)sr * HDIM + kc + sc]);
    *(uint4*)&Ah[sr * LDA + sc] = qa.hi;
    *(uint4*)&Al[sr * LDA + sc] = qa.lo;
    *(uint4*)&Bh[sr * LDA + sc] = eb.hi;
    *(uint4*)&Bl[sr * LDA + sc] = eb.lo;
    __syncthreads();
    bf16x8 ah = *(const bf16x8*)&Ah[(w * 16 + la) * LDA + quad * 8];
    bf16x8 al = *(const bf16x8*)&Al[(w * 16 + la) * LDA + quad * 8];
#pragma unroll
    for (int n = 0; n < 4; ++n) {
      bf16x8 bh = *(const bf16x8*)&Bh[(n * 16 + la) * LDA + quad * 8];
      bf16x8 bl = *(const bf16x8*)&Bl[(n * 16 + la) * LDA + quad * 8];
      acc[n] = __builtin_amdgcn_mfma_f32_16x16x32_bf16(ah, bh, acc[n], 0, 0, 0);
      acc[n] = __builtin_amdgcn_mfma_f32_16x16x32_bf16(ah, bl, acc[n], 0, 0, 0);
      acc[n] = __builtin_amdgcn_mfma_f32_16x16x32_bf16(al, bh, acc[n], 0, 0, 0);
    }
    __syncthreads();
  }

  float* Sb = S + ((size_t)b * OLEN + ot * 64) * (size_t)ILEN + it * 64;
#pragma unroll
  for (int n = 0; n < 4; ++n)
#pragma unroll
    for (int r = 0; r < 4; ++r)
      Sb[(size_t)(w * 16 + quad * 4 + r) * ILEN + n * 16 + la] = acc[n][r];
}

__global__ __launch_bounds__(256) void k_context_f32(const float* __restrict__ P,
                                                     const short* __restrict__ ET,
                                                     float* __restrict__ C) {
  const int ot = blockIdx.x, ht = blockIdx.y, b = blockIdx.z;
  const float* Pb = P + ((size_t)b * OLEN + ot * 64) * (size_t)ILEN;
  const short* Tb = ET + ((size_t)b * HDIM + ht * 64) * (size_t)ILEN;

  __shared__ __align__(16) short As[64 * LDA], Bs[64 * LDA];

  const int t = threadIdx.x;
  const int w = t >> 6, l = t & 63;
  const int la = l & 15, quad = l >> 4;
  const int sr = t >> 2, sc = (t & 3) * 8;

  f32x4 acc[4] = {};

  for (int ic = 0; ic < ILEN; ic += 32) {
    {
      float4 p0 = *(const float4*)&Pb[(size_t)sr * ILEN + ic + sc];
      float4 p1 = *(const float4*)&Pb[(size_t)sr * ILEN + ic + sc + 4];
      uint4 aw = make_uint4(pk_bf16(p0.x, p0.y), pk_bf16(p0.z, p0.w),
                            pk_bf16(p1.x, p1.y), pk_bf16(p1.z, p1.w));
      *(uint4*)&As[sr * LDA + sc] = aw;
      uint4 bw = *(const uint4*)&Tb[(size_t)sr * ILEN + ic + sc];
      *(uint4*)&Bs[sr * LDA + sc] = bw;
    }
    __syncthreads();
    bf16x8 a = *(const bf16x8*)&As[(w * 16 + la) * LDA + quad * 8];
#pragma unroll
    for (int n = 0; n < 4; ++n) {
      bf16x8 bb = *(const bf16x8*)&Bs[(n * 16 + la) * LDA + quad * 8];
      acc[n] = __builtin_amdgcn_mfma_f32_16x16x32_bf16(a, bb, acc[n], 0, 0, 0);
    }
    __syncthreads();
  }

  float* Cb = C + ((size_t)b * OLEN + ot * 64) * HDIM + ht * 64;
#pragma unroll
  for (int n = 0; n < 4; ++n)
#pragma unroll
    for (int r = 0; r < 4; ++r)
      Cb[(size_t)(w * 16 + quad * 4 + r) * HDIM + n * 16 + la] = acc[n][r];
}

extern "C" void kernel_launch(void* const* d_in, const int* in_sizes, int n_in,
                              void* d_out, int out_size, void* d_ws, size_t ws_size,
                              hipStream_t stream) {
  (void)in_sizes; (void)n_in; (void)out_size;
  const float* outp = (const float*)d_in[0];  // [B, OLEN, H]
  const float* enc  = (const float*)d_in[1];  // [B, ILEN, H]
  const int*   len  = (const int*)d_in[2];    // [B]

  float* ctx  = (float*)d_out;
  float* attn = ctx + (size_t)B_ * OLEN * HDIM;

  short* ws = (short*)d_ws;
  const size_t M = 1024 * 1024;
  // ws layout (shorts): ET[0,8M) Qhi[8M,10M) Qlo[10M,12M) Ehi[12M,20M) Elo[20M,28M)
  // = 56 MB total. Cpart (fp32, KSPLIT x 8.4 MB = 33.6 MB) overlays bytes
  // [16M, 49.6M) — dead after k_scores_pre.
  // Per-tile stats live in ctx[0..2MB) (dead until k_reduce rewrites ctx).
  short* ET = ws;

  if (ws_size >= 56ull * 1024 * 1024) {
    short* Qhi = ws + 8 * M;
    short* Qlo = ws + 10 * M;
    short* Ehi = ws + 12 * M;
    short* Elo = ws + 20 * M;
    float* Cpart = (float*)(ws + 8 * M);  // byte offset 16 MB; 33.6 MB used
    float2* stat = (float2*)ctx;          // 2 MB

    k_prep<<<dim3(ILEN / 32, 9, B_), 256, 0, stream>>>(outp, enc, Qhi, Qlo,
                                                       Ehi, Elo, ET, len);
    dim3 g1(ILEN / 128, OLEN / 128, B_);
    k_scores_pre<<<g1, 256, 0, stream>>>(Qhi, Qlo, Ehi, Elo, attn, stat, len);
    dim3 g3(OLEN / 32, KSPLIT, B_);
    k_context_fused<<<g3, 256, 0, stream>>>(attn, ET, Cpart, stat, len);
    k_reduce<<<(B_ * OLEN * HDIM) / (256 * 8), 256, 0, stream>>>(Cpart, ctx);
  } else {
    dim3 gt(ILEN / 32, HDIM / 32, B_);
    k_etrans<<<gt, 256, 0, stream>>>(enc, ET);
    k_scores_split<<<dim3(ILEN / 64, OLEN / 64, B_), 256, 0, stream>>>(outp, enc, attn);
    k_softmax<<<B_ * OLEN, 256, 0, stream>>>(attn, len);
    dim3 g3(OLEN / 64, HDIM / 64, B_);
    k_context_f32<<<g3, 256, 0, stream>>>(attn, ET, ctx);
  }
}